// Round 3
// baseline (5357.445 us; speedup 1.0000x reference)
//
#include <hip/hip_runtime.h>

#define Bb 32
#define Tt 512
#define Dd 256
#define Pp 512
#define Hh 512
#define G4 2048
#define TC 128   // time-chunk length (4 chunks)
#define NG 8     // batch groups (XCD-aligned via blockIdx%8)
#define WPG 32   // workgroups per group (grid = 256)
#define NBG 4    // batches per group

__device__ __forceinline__ float sigmf(float x){ return 1.0f/(1.0f+__expf(-x)); }
__device__ __forceinline__ float tanhf_(float x){ return 1.0f - 2.0f/(__expf(2.0f*x)+1.0f); }

// out[m] = sum_k A[m,k]^2
__global__ void k_rowsq(const float* __restrict__ A, float* __restrict__ o, int M, int K){
  int m = blockIdx.x*blockDim.x + threadIdx.x;
  if (m >= M) return;
  const float4* a4 = (const float4*)(A + (size_t)m*K);
  float s = 0.f;
  for (int i = 0; i < K/4; ++i){ float4 v = a4[i]; s += v.x*v.x + v.y*v.y + v.z*v.z + v.w*v.w; }
  o[m] = s;
}

// out (N x M) = in (M x N)^T
__global__ void k_transpose(const float* __restrict__ in, float* __restrict__ out, int M, int N){
  __shared__ float tile[32][33];
  int bn = blockIdx.x * 32;
  int bm = blockIdx.y * 32;
  int tx = threadIdx.x, ty = threadIdx.y; // block (32,8)
  #pragma unroll
  for (int i = 0; i < 32; i += 8)
    tile[ty+i][tx] = in[(size_t)(bm+ty+i)*N + bn+tx];
  __syncthreads();
  #pragma unroll
  for (int i = 0; i < 32; i += 8)
    out[(size_t)(bn+ty+i)*M + bm+tx] = tile[tx][ty+i];
}

// bx[r] = dot(W_ih[r,:], b_lin) + b_ih[r] + b_hh[r]
__global__ void k_bx(const float* __restrict__ Wih, const float* __restrict__ blin,
                     const float* __restrict__ bih, const float* __restrict__ bhh,
                     float* __restrict__ bx){
  int r = blockIdx.x*blockDim.x + threadIdx.x; // 2048 threads
  const float4* w4 = (const float4*)(Wih + (size_t)r*Hh);
  const float4* b4 = (const float4*)blin;
  float s = 0.f;
  for (int i = 0; i < Hh/4; ++i){ float4 w=w4[i], b=b4[i]; s += w.x*b.x+w.y*b.y+w.z*b.z+w.w*b.w; }
  bx[r] = s + bih[r] + bhh[r];
}

// Generic tiled fp32 GEMM: C[M,N] = epi(A[M,K] @ B[K,N])
// EPI 0: none. EPI 1: exp(-max(rowAux[m]+colAux[n]-2*acc,0)). EPI 2: acc+colAux[n].
// REMAP: A-row (and rowAux) index m -> (m>>7)*Tt + t0 + (m&127); C stays dense.
template<int EPI, bool REMAP>
__global__ __launch_bounds__(256) void k_gemm(const float* __restrict__ A, const float* __restrict__ Bm,
                                              float* __restrict__ C, int M, int N, int K,
                                              const float* __restrict__ rowAux,
                                              const float* __restrict__ colAux, int t0)
{
  __shared__ float As[16][132];
  __shared__ float Bs[16][68];
  const int tid = threadIdx.x;
  const int bm = blockIdx.x * 128;
  const int bn = blockIdx.y * 64;
  const int tm = (tid & 15) * 8;
  const int tn = (tid >> 4) * 4;
  const int arow = tid >> 1;
  const int akq  = (tid & 1) * 8;
  const int brow = tid >> 4;
  const int bcol = (tid & 15) * 4;
  const int am = bm + arow;
  const size_t aRow = REMAP ? ((size_t)(am >> 7) * Tt + t0 + (am & 127)) : (size_t)am;
  float acc[8][4] = {};
  for (int k0 = 0; k0 < K; k0 += 16){
    float4 a0 = *(const float4*)&A[aRow*K + k0 + akq];
    float4 a1 = *(const float4*)&A[aRow*K + k0 + akq + 4];
    float4 bv = *(const float4*)&Bm[(size_t)(k0 + brow)*N + bn + bcol];
    As[akq+0][arow]=a0.x; As[akq+1][arow]=a0.y; As[akq+2][arow]=a0.z; As[akq+3][arow]=a0.w;
    As[akq+4][arow]=a1.x; As[akq+5][arow]=a1.y; As[akq+6][arow]=a1.z; As[akq+7][arow]=a1.w;
    *(float4*)&Bs[brow][bcol] = bv;
    __syncthreads();
    #pragma unroll
    for (int kk = 0; kk < 16; ++kk){
      float4 x0 = *(const float4*)&As[kk][tm];
      float4 x1 = *(const float4*)&As[kk][tm+4];
      float4 y  = *(const float4*)&Bs[kk][tn];
      float av[8] = {x0.x,x0.y,x0.z,x0.w,x1.x,x1.y,x1.z,x1.w};
      #pragma unroll
      for (int i=0;i<8;++i){
        float a = av[i];
        acc[i][0] += a*y.x; acc[i][1] += a*y.y; acc[i][2] += a*y.z; acc[i][3] += a*y.w;
      }
    }
    __syncthreads();
  }
  #pragma unroll
  for (int i=0;i<8;++i){
    int m = bm + tm + i;
    size_t mAux = REMAP ? ((size_t)(m >> 7) * Tt + t0 + (m & 127)) : (size_t)m;
    float4 o;
    float vv[4];
    #pragma unroll
    for (int j=0;j<4;++j){
      int n = bn + tn + j;
      float v = acc[i][j];
      if (EPI==1)      v = __expf(-fmaxf(rowAux[mAux] + colAux[n] - 2.f*v, 0.f));
      else if (EPI==2) v = v + colAux[n];
      vv[j] = v;
    }
    o.x=vv[0]; o.y=vv[1]; o.z=vv[2]; o.w=vv[3];
    *(float4*)&C[(size_t)m*N + bn + tn] = o;
  }
}

// Persistent LSTM over one time-chunk of TC steps.
// Grid: 256 WGs x 512 thr, cooperative. group gid = blockIdx%8 (4 batches),
// wg = blockIdx/8 in [0,32) owns 16 hidden units j in [wg*16, wg*16+16).
// Thread tid = ug*64 + ks*4 + gsel holds W_hh rows (gsel*512 + wg*16+ug*2+r),
// r<2, k in [32ks,32ks+32): W[2][32] = 64 VGPRs, pinned via asm.
// Sync: per-WG monotonic flag (release store / acquire poll, agent scope);
// h exchanged through `out` with relaxed agent-scope atomics.
__global__ __launch_bounds__(512, 2) void k_lstm_persist(
    const float* __restrict__ Whh, const float* __restrict__ xs,
    float* __restrict__ cbuf, float* __restrict__ out,
    unsigned* __restrict__ flags, int t0)
{
  __shared__ float hbuf[NBG*Hh];   // 8 KB, swizzled
  const int tid  = threadIdx.x;
  const int gid  = blockIdx.x & 7;
  const int wg   = blockIdx.x >> 3;
  const int gsel = tid & 3;
  const int ks   = (tid >> 2) & 15;
  const int ug   = tid >> 6;
  const int jbase = wg*16 + ug*2;

  // ---- load W slice into registers (once per chunk), pin in VGPRs ----
  float W[2][32];
  #pragma unroll
  for (int r = 0; r < 2; ++r){
    const float* wrow = &Whh[(size_t)(gsel*Hh + jbase + r)*Hh + ks*32];
    #pragma unroll
    for (int c = 0; c < 8; ++c){
      float4 w = *(const float4*)&wrow[c*4];
      W[r][c*4+0]=w.x; W[r][c*4+1]=w.y; W[r][c*4+2]=w.z; W[r][c*4+3]=w.w;
    }
  }
  #pragma unroll
  for (int r = 0; r < 2; ++r)
    #pragma unroll
    for (int c = 0; c < 32; ++c)
      asm volatile("" : "+v"(W[r][c]));

  // this lane's post-reduction output identity (valid when ks < 8)
  const int rr = ks >> 2;          // 0..1 (for ks<8)
  const int bl = ks & 3;
  const int j  = jbase + (rr & 1);
  const int b  = gid*NBG + bl;
  float c_st = (t0 == 0) ? 0.f : cbuf[(size_t)b*Hh + j];

  // h-stage assignment: thread stages 4 floats of h
  const int sbl = tid >> 7;           // batch-local 0..3
  const int skb = (tid & 127) * 4;    // k base
  const int ssw = skb ^ (((skb >> 5) & 7) << 2);

  for (int tl = 0; tl < TC; ++tl){
    const int t = t0 + tl;

    // ---- wait for all producer WGs of this group to finish step t-1 ----
    if (t > 0 && tid < 64){
      const unsigned tgt = (unsigned)t;
      const unsigned fi = gid*WPG + (tid & (WPG-1));
      for (;;){
        unsigned f = __hip_atomic_load(&flags[fi], __ATOMIC_ACQUIRE, __HIP_MEMORY_SCOPE_AGENT);
        if (__all((int)(f >= tgt))) break;
      }
    }
    __syncthreads();

    // ---- stage h(t-1) into swizzled LDS ----
    float4 hv = {0.f,0.f,0.f,0.f};
    if (t > 0){
      const float* src = &out[((size_t)(gid*NBG + sbl)*Tt + (t-1))*Hh + skb];
      hv.x = __hip_atomic_load(src+0, __ATOMIC_RELAXED, __HIP_MEMORY_SCOPE_AGENT);
      hv.y = __hip_atomic_load(src+1, __ATOMIC_RELAXED, __HIP_MEMORY_SCOPE_AGENT);
      hv.z = __hip_atomic_load(src+2, __ATOMIC_RELAXED, __HIP_MEMORY_SCOPE_AGENT);
      hv.w = __hip_atomic_load(src+3, __ATOMIC_RELAXED, __HIP_MEMORY_SCOPE_AGENT);
    }
    *(float4*)&hbuf[sbl*Hh + ssw] = hv;
    __syncthreads();

    // ---- GEMV: acc[r][bl] += W[r][k] * h[bl][k] over this thread's k-slice ----
    float acc[2][4];
    #pragma unroll
    for (int r=0;r<2;++r){ acc[r][0]=0.f; acc[r][1]=0.f; acc[r][2]=0.f; acc[r][3]=0.f; }
    #pragma unroll
    for (int blq = 0; blq < 4; ++blq){
      const float* hb = &hbuf[blq*Hh + ks*32];
      #pragma unroll
      for (int c = 0; c < 8; ++c){
        float4 h4 = *(const float4*)&hb[(c*4) ^ ((ks & 7) << 2)];
        #pragma unroll
        for (int r = 0; r < 2; ++r){
          acc[r][blq] = fmaf(W[r][c*4+0], h4.x, acc[r][blq]);
          acc[r][blq] = fmaf(W[r][c*4+1], h4.y, acc[r][blq]);
          acc[r][blq] = fmaf(W[r][c*4+2], h4.z, acc[r][blq]);
          acc[r][blq] = fmaf(W[r][c*4+3], h4.w, acc[r][blq]);
        }
      }
    }

    // ---- in-wave reduction over ks (lane bits 2-5) ----
    #pragma unroll
    for (int m = 4; m <= 32; m <<= 1){
      #pragma unroll
      for (int r=0;r<2;++r){
        #pragma unroll
        for (int q=0;q<4;++q)
          acc[r][q] += __shfl_xor(acc[r][q], m, 64);
      }
    }
    // lane with ks = r*4+q (ks<8) takes entry (r,q)
    float g = acc[0][0];
    #pragma unroll
    for (int r=0;r<2;++r)
      #pragma unroll
      for (int q=0;q<4;++q)
        if (ks == r*4+q) g = acc[r][q];

    // ---- add xs (only meaningful lanes), collect 4 gates, update c,h ----
    if (ks < 8)
      g += xs[((size_t)b*TC + tl)*G4 + gsel*Hh + j];
    const int lbase = (tid & 63) & ~3;
    float gi = __shfl(g, lbase+0, 64);
    float gf = __shfl(g, lbase+1, 64);
    float gg = __shfl(g, lbase+2, 64);
    float go = __shfl(g, lbase+3, 64);
    gi = sigmf(gi); gf = sigmf(gf); gg = tanhf_(gg); go = sigmf(go);
    c_st = gf*c_st + gi*gg;
    float h = go * tanhf_(c_st);
    if (gsel == 0 && ks < 8)
      __hip_atomic_store(&out[((size_t)b*Tt + t)*Hh + j], h,
                         __ATOMIC_RELAXED, __HIP_MEMORY_SCOPE_AGENT);
    __syncthreads();   // every wave drains vmcnt before barrier -> h globally complete

    // ---- publish: this WG finished step t ----
    if (tid == 0)
      __hip_atomic_store(&flags[gid*WPG + wg], (unsigned)(t + 1),
                         __ATOMIC_RELEASE, __HIP_MEMORY_SCOPE_AGENT);
  }
  if (gsel == 0 && ks < 8) cbuf[(size_t)b*Hh + j] = c_st;
}

extern "C" void kernel_launch(void* const* d_in, const int* in_sizes, int n_in,
                              void* d_out, int out_size, void* d_ws, size_t ws_size,
                              hipStream_t stream)
{
  const float* x    = (const float*)d_in[0];
  const float* prot = (const float*)d_in[1];
  const float* Wlin = (const float*)d_in[2];
  const float* blin = (const float*)d_in[3];
  const float* Wih  = (const float*)d_in[4];
  const float* Whh  = (const float*)d_in[5];
  const float* bih  = (const float*)d_in[6];
  const float* bhh  = (const float*)d_in[7];
  float* out = (float*)d_out;
  float* ws  = (float*)d_ws;

  size_t off = 0;
  auto alloc = [&](size_t n)->float*{ float* p = ws + off; off += (n + 15) & ~((size_t)15); return p; };
  float* x2    = alloc((size_t)Bb*Tt);
  float* p2    = alloc(Pp);
  float* pT    = alloc((size_t)Dd*Pp);
  float* bx    = alloc(G4);
  float* Wx    = alloc((size_t)G4*Pp);
  float* WxT   = alloc((size_t)Pp*G4);
  float* cbuf  = alloc((size_t)Bb*Hh);
  float* featsC= alloc((size_t)Bb*TC*Pp);
  float* xsC   = alloc((size_t)Bb*TC*G4);
  unsigned* flags = (unsigned*)alloc(NG*WPG);
  // total ~13.6M floats ~ 55 MB

  // ---- setup ----
  k_rowsq<<<dim3((Bb*Tt)/256), dim3(256), 0, stream>>>(x, x2, Bb*Tt, Dd);
  k_rowsq<<<dim3(Pp/256), dim3(256), 0, stream>>>(prot, p2, Pp, Dd);
  k_transpose<<<dim3(Dd/32, Pp/32), dim3(32,8), 0, stream>>>(prot, pT, Pp, Dd);
  k_bx<<<dim3(G4/256), dim3(256), 0, stream>>>(Wih, blin, bih, bhh, bx);
  k_gemm<0,false><<<dim3(G4/128, Pp/64), dim3(256), 0, stream>>>(Wih, Wlin, Wx, G4, Pp, Hh, nullptr, nullptr, 0);
  k_transpose<<<dim3(Pp/32, G4/32), dim3(32,8), 0, stream>>>(Wx, WxT, G4, Pp);
  hipMemsetAsync(flags, 0, NG*WPG*sizeof(unsigned), stream);   // reset every launch (graph-replayed)

  // ---- main: 4 time-chunks of 128 steps ----
  for (int ch = 0; ch < Tt/TC; ++ch){
    int t0 = ch * TC;
    k_gemm<1,true><<<dim3((Bb*TC)/128, Pp/64), dim3(256), 0, stream>>>(
        x, pT, featsC, Bb*TC, Pp, Dd, x2, p2, t0);
    k_gemm<2,false><<<dim3((Bb*TC)/128, G4/64), dim3(256), 0, stream>>>(
        featsC, WxT, xsC, Bb*TC, G4, Pp, nullptr, bx, 0);
    void* args[] = { (void*)&Whh, (void*)&xsC, (void*)&cbuf, (void*)&out, (void*)&flags, (void*)&t0 };
    hipLaunchCooperativeKernel((void*)k_lstm_persist, dim3(NG*WPG), dim3(512), args, 0, stream);
  }
}

// Round 5
// 4333.324 us; speedup vs baseline: 1.2363x; 1.2363x over previous
//
#include <hip/hip_runtime.h>

#define Bb 32
#define Tt 512
#define Dd 256
#define Pp 512
#define Hh 512
#define G4 2048
#define TC 128   // time-chunk length (4 chunks)
#define NG 16    // batch groups (2 batches each)
#define WPG 16   // workgroups per group (grid = 256)
#define NBG 2    // batches per group

__device__ __forceinline__ float sigmf(float x){ return 1.0f/(1.0f+__expf(-x)); }
__device__ __forceinline__ float tanhf_(float x){ return 1.0f - 2.0f/(__expf(2.0f*x)+1.0f); }

// out[m] = sum_k A[m,k]^2
__global__ void k_rowsq(const float* __restrict__ A, float* __restrict__ o, int M, int K){
  int m = blockIdx.x*blockDim.x + threadIdx.x;
  if (m >= M) return;
  const float4* a4 = (const float4*)(A + (size_t)m*K);
  float s = 0.f;
  for (int i = 0; i < K/4; ++i){ float4 v = a4[i]; s += v.x*v.x + v.y*v.y + v.z*v.z + v.w*v.w; }
  o[m] = s;
}

// out (N x M) = in (M x N)^T
__global__ void k_transpose(const float* __restrict__ in, float* __restrict__ out, int M, int N){
  __shared__ float tile[32][33];
  int bn = blockIdx.x * 32;
  int bm = blockIdx.y * 32;
  int tx = threadIdx.x, ty = threadIdx.y; // block (32,8)
  #pragma unroll
  for (int i = 0; i < 32; i += 8)
    tile[ty+i][tx] = in[(size_t)(bm+ty+i)*N + bn+tx];
  __syncthreads();
  #pragma unroll
  for (int i = 0; i < 32; i += 8)
    out[(size_t)(bn+ty+i)*M + bm+tx] = tile[tx][ty+i];
}

// bx[r] = dot(W_ih[r,:], b_lin) + b_ih[r] + b_hh[r]
__global__ void k_bx(const float* __restrict__ Wih, const float* __restrict__ blin,
                     const float* __restrict__ bih, const float* __restrict__ bhh,
                     float* __restrict__ bx){
  int r = blockIdx.x*blockDim.x + threadIdx.x; // 2048 threads
  const float4* w4 = (const float4*)(Wih + (size_t)r*Hh);
  const float4* b4 = (const float4*)blin;
  float s = 0.f;
  for (int i = 0; i < Hh/4; ++i){ float4 w=w4[i], b=b4[i]; s += w.x*b.x+w.y*b.y+w.z*b.z+w.w*b.w; }
  bx[r] = s + bih[r] + bhh[r];
}

// Generic tiled fp32 GEMM: C[M,N] = epi(A[M,K] @ B[K,N])
// EPI 0: none. EPI 1: exp(-max(rowAux[m]+colAux[n]-2*acc,0)). EPI 2: acc+colAux[n].
// REMAP: A-row (and rowAux) index m -> (m>>7)*Tt + t0 + (m&127); C stays dense.
template<int EPI, bool REMAP>
__global__ __launch_bounds__(256) void k_gemm(const float* __restrict__ A, const float* __restrict__ Bm,
                                              float* __restrict__ C, int M, int N, int K,
                                              const float* __restrict__ rowAux,
                                              const float* __restrict__ colAux, int t0)
{
  __shared__ float As[16][132];
  __shared__ float Bs[16][68];
  const int tid = threadIdx.x;
  const int bm = blockIdx.x * 128;
  const int bn = blockIdx.y * 64;
  const int tm = (tid & 15) * 8;
  const int tn = (tid >> 4) * 4;
  const int arow = tid >> 1;
  const int akq  = (tid & 1) * 8;
  const int brow = tid >> 4;
  const int bcol = (tid & 15) * 4;
  const int am = bm + arow;
  const size_t aRow = REMAP ? ((size_t)(am >> 7) * Tt + t0 + (am & 127)) : (size_t)am;
  float acc[8][4] = {};
  for (int k0 = 0; k0 < K; k0 += 16){
    float4 a0 = *(const float4*)&A[aRow*K + k0 + akq];
    float4 a1 = *(const float4*)&A[aRow*K + k0 + akq + 4];
    float4 bv = *(const float4*)&Bm[(size_t)(k0 + brow)*N + bn + bcol];
    As[akq+0][arow]=a0.x; As[akq+1][arow]=a0.y; As[akq+2][arow]=a0.z; As[akq+3][arow]=a0.w;
    As[akq+4][arow]=a1.x; As[akq+5][arow]=a1.y; As[akq+6][arow]=a1.z; As[akq+7][arow]=a1.w;
    *(float4*)&Bs[brow][bcol] = bv;
    __syncthreads();
    #pragma unroll
    for (int kk = 0; kk < 16; ++kk){
      float4 x0 = *(const float4*)&As[kk][tm];
      float4 x1 = *(const float4*)&As[kk][tm+4];
      float4 y  = *(const float4*)&Bs[kk][tn];
      float av[8] = {x0.x,x0.y,x0.z,x0.w,x1.x,x1.y,x1.z,x1.w};
      #pragma unroll
      for (int i=0;i<8;++i){
        float a = av[i];
        acc[i][0] += a*y.x; acc[i][1] += a*y.y; acc[i][2] += a*y.z; acc[i][3] += a*y.w;
      }
    }
    __syncthreads();
  }
  #pragma unroll
  for (int i=0;i<8;++i){
    int m = bm + tm + i;
    size_t mAux = REMAP ? ((size_t)(m >> 7) * Tt + t0 + (m & 127)) : (size_t)m;
    float4 o;
    float vv[4];
    #pragma unroll
    for (int j=0;j<4;++j){
      int n = bn + tn + j;
      float v = acc[i][j];
      if (EPI==1)      v = __expf(-fmaxf(rowAux[mAux] + colAux[n] - 2.f*v, 0.f));
      else if (EPI==2) v = v + colAux[n];
      vv[j] = v;
    }
    o.x=vv[0]; o.y=vv[1]; o.z=vv[2]; o.w=vv[3];
    *(float4*)&C[(size_t)m*N + bn + tn] = o;
  }
}

// Persistent LSTM over one time-chunk of TC steps.
// Grid: 256 WGs x 512 thr, cooperative. Group gid = blockIdx&15 owns batches
// {2gid, 2gid+1}; wg = blockIdx>>4 owns j in [wg*32, wg*32+32).
// Thread: wave wv (0..7), lane; ks = lane>>4 (k quarter), row = wv*16+(lane&15)
// -> gate gsel=row&3 of j = wg*32 + (row>>2). W[128] = the (gsel,j) row's k-slice,
// register-resident (pinned via asm + amdgpu_waves_per_eu(2,2) -> 256-VGPR budget).
// Sync (the round-4 fix): poll flags with RELAXED loads (no per-iteration inv),
// then ONE acquire fence; producers __syncthreads (drains all waves' vmcnt),
// then ONE release fence + relaxed flag store. Proven-correct acquire/release
// semantics (rounds 2/3) at 1 inv + 1 wbl2 per WG per step instead of per poll.
__global__ __launch_bounds__(512) __attribute__((amdgpu_waves_per_eu(2, 2)))
void k_lstm_persist(const float* __restrict__ Whh, const float* __restrict__ xs,
                    float* __restrict__ cbuf, float* __restrict__ out,
                    unsigned* __restrict__ flags, int t0)
{
  __shared__ float hbuf[NBG][4][136];   // padded: ks rows 8 banks apart
  const int tid  = threadIdx.x;
  const int lane = tid & 63;
  const int wv   = tid >> 6;
  const int ks   = lane >> 4;
  const int row  = wv*16 + (lane & 15);
  const int gsel = row & 3;
  const int gid  = blockIdx.x & 15;
  const int wg   = blockIdx.x >> 4;
  const int j    = wg*32 + (row >> 2);

  // ---- load W row-slice into registers (once per chunk), pin ----
  float W[128];
  {
    const float* wr = &Whh[(size_t)(gsel*Hh + j)*Hh + ks*128];
    #pragma unroll
    for (int c = 0; c < 32; ++c){
      float4 w = *(const float4*)&wr[c*4];
      W[c*4+0]=w.x; W[c*4+1]=w.y; W[c*4+2]=w.z; W[c*4+3]=w.w;
    }
  }
  #pragma unroll
  for (int c = 0; c < 128; ++c) asm volatile("" : "+v"(W[c]));

  // gate-group identity: 4 lanes (base..base+3, same ks) share jown
  const int jown = wg*32 + wv*4 + ((lane & 12) >> 2);
  float c_st[NBG];
  #pragma unroll
  for (int bl = 0; bl < NBG; ++bl)
    c_st[bl] = (t0 == 0) ? 0.f : cbuf[(size_t)(gid*NBG + bl)*Hh + jown];

  // h-stage identity: 1024 floats over 512 threads (2 each)
  const int sbl = tid >> 8;
  const int skk = (tid & 255) * 2;

  for (int tl = 0; tl < TC; ++tl){
    const int t = t0 + tl;

    // prefetch xs (independent of h)
    float xv[NBG];
    #pragma unroll
    for (int bl = 0; bl < NBG; ++bl)
      xv[bl] = xs[((size_t)(gid*NBG + bl)*TC + tl)*G4 + gsel*Hh + j];

    // ---- wait for all producers of this group: relaxed spin + ONE acquire fence ----
    if (t > 0){
      if (wv == 0){
        const unsigned tgt = (unsigned)t;
        for (;;){
          unsigned f = __hip_atomic_load(&flags[gid*WPG + (lane & 15)],
                                         __ATOMIC_RELAXED, __HIP_MEMORY_SCOPE_AGENT);
          if (__all((int)(f >= tgt))) break;
        }
        __builtin_amdgcn_fence(__ATOMIC_ACQUIRE, "agent");   // one inv per WG per step
      }
      __syncthreads();
    }

    // ---- stage h(t-1) into LDS ----
    float h0 = 0.f, h1 = 0.f;
    if (t > 0){
      const float* src = &out[((size_t)(gid*NBG + sbl)*Tt + (t-1))*Hh + skk];
      h0 = __hip_atomic_load(src+0, __ATOMIC_RELAXED, __HIP_MEMORY_SCOPE_AGENT);
      h1 = __hip_atomic_load(src+1, __ATOMIC_RELAXED, __HIP_MEMORY_SCOPE_AGENT);
    }
    {
      float2 hw; hw.x = h0; hw.y = h1;
      *(float2*)&hbuf[sbl][skk>>7][skk&127] = hw;
    }
    __syncthreads();

    // ---- GEMV: 256 FMA vs register W, broadcast LDS h ----
    float a0 = 0.f, a1 = 0.f;
    {
      const float* hb0 = &hbuf[0][ks][0];
      const float* hb1 = &hbuf[1][ks][0];
      #pragma unroll
      for (int c = 0; c < 32; ++c){
        float4 p = *(const float4*)&hb0[c*4];
        float4 q = *(const float4*)&hb1[c*4];
        a0 = fmaf(W[c*4+0],p.x,a0); a0 = fmaf(W[c*4+1],p.y,a0);
        a0 = fmaf(W[c*4+2],p.z,a0); a0 = fmaf(W[c*4+3],p.w,a0);
        a1 = fmaf(W[c*4+0],q.x,a1); a1 = fmaf(W[c*4+1],q.y,a1);
        a1 = fmaf(W[c*4+2],q.z,a1); a1 = fmaf(W[c*4+3],q.w,a1);
      }
    }
    // reduce over ks (lane bits 4,5)
    a0 += __shfl_xor(a0, 16, 64); a0 += __shfl_xor(a0, 32, 64);
    a1 += __shfl_xor(a1, 16, 64); a1 += __shfl_xor(a1, 32, 64);
    a0 += xv[0]; a1 += xv[1];

    // gather 4 gates from adjacent lanes (every lane computes; subset stores)
    const int base = lane & ~3;
    float gi0=__shfl(a0,base+0,64), gf0=__shfl(a0,base+1,64),
          gg0=__shfl(a0,base+2,64), go0=__shfl(a0,base+3,64);
    float gi1=__shfl(a1,base+0,64), gf1=__shfl(a1,base+1,64),
          gg1=__shfl(a1,base+2,64), go1=__shfl(a1,base+3,64);
    gi0=sigmf(gi0); gf0=sigmf(gf0); gg0=tanhf_(gg0); go0=sigmf(go0);
    gi1=sigmf(gi1); gf1=sigmf(gf1); gg1=tanhf_(gg1); go1=sigmf(go1);
    c_st[0] = gf0*c_st[0] + gi0*gg0;
    c_st[1] = gf1*c_st[1] + gi1*gg1;
    float hh0 = go0 * tanhf_(c_st[0]);
    float hh1 = go1 * tanhf_(c_st[1]);
    if (ks == 0 && (lane & 3) == 0){
      __hip_atomic_store(&out[((size_t)(gid*NBG+0)*Tt + t)*Hh + jown], hh0,
                         __ATOMIC_RELAXED, __HIP_MEMORY_SCOPE_AGENT);
      __hip_atomic_store(&out[((size_t)(gid*NBG+1)*Tt + t)*Hh + jown], hh1,
                         __ATOMIC_RELAXED, __HIP_MEMORY_SCOPE_AGENT);
    }
    __syncthreads();   // every wave drains vmcnt -> all h-stores complete in L2

    // ---- publish: ONE release fence (wbl2) + relaxed flag store ----
    if (tid == 0){
      __builtin_amdgcn_fence(__ATOMIC_RELEASE, "agent");
      __hip_atomic_store(&flags[gid*WPG + wg], (unsigned)(t + 1),
                         __ATOMIC_RELAXED, __HIP_MEMORY_SCOPE_AGENT);
    }
  }

  if (ks == 0 && (lane & 3) == 0){
    cbuf[(size_t)(gid*NBG+0)*Hh + jown] = c_st[0];
    cbuf[(size_t)(gid*NBG+1)*Hh + jown] = c_st[1];
  }
}

extern "C" void kernel_launch(void* const* d_in, const int* in_sizes, int n_in,
                              void* d_out, int out_size, void* d_ws, size_t ws_size,
                              hipStream_t stream)
{
  const float* x    = (const float*)d_in[0];
  const float* prot = (const float*)d_in[1];
  const float* Wlin = (const float*)d_in[2];
  const float* blin = (const float*)d_in[3];
  const float* Wih  = (const float*)d_in[4];
  const float* Whh  = (const float*)d_in[5];
  const float* bih  = (const float*)d_in[6];
  const float* bhh  = (const float*)d_in[7];
  float* out = (float*)d_out;
  float* ws  = (float*)d_ws;

  size_t off = 0;
  auto alloc = [&](size_t n)->float*{ float* p = ws + off; off += (n + 15) & ~((size_t)15); return p; };
  float* x2    = alloc((size_t)Bb*Tt);
  float* p2    = alloc(Pp);
  float* pT    = alloc((size_t)Dd*Pp);
  float* bx    = alloc(G4);
  float* Wx    = alloc((size_t)G4*Pp);
  float* WxT   = alloc((size_t)Pp*G4);
  float* cbuf  = alloc((size_t)Bb*Hh);
  float* featsC= alloc((size_t)Bb*TC*Pp);
  float* xsC   = alloc((size_t)Bb*TC*G4);
  unsigned* flags = (unsigned*)alloc(NG*WPG);
  // total ~13.6M floats ~ 55 MB

  // ---- setup ----
  k_rowsq<<<dim3((Bb*Tt)/256), dim3(256), 0, stream>>>(x, x2, Bb*Tt, Dd);
  k_rowsq<<<dim3(Pp/256), dim3(256), 0, stream>>>(prot, p2, Pp, Dd);
  k_transpose<<<dim3(Dd/32, Pp/32), dim3(32,8), 0, stream>>>(prot, pT, Pp, Dd);
  k_bx<<<dim3(G4/256), dim3(256), 0, stream>>>(Wih, blin, bih, bhh, bx);
  k_gemm<0,false><<<dim3(G4/128, Pp/64), dim3(256), 0, stream>>>(Wih, Wlin, Wx, G4, Pp, Hh, nullptr, nullptr, 0);
  k_transpose<<<dim3(Pp/32, G4/32), dim3(32,8), 0, stream>>>(Wx, WxT, G4, Pp);
  hipMemsetAsync(flags, 0, NG*WPG*sizeof(unsigned), stream);   // reset every launch (in-graph)

  // ---- main: 4 time-chunks of 128 steps ----
  for (int ch = 0; ch < Tt/TC; ++ch){
    int t0 = ch * TC;
    k_gemm<1,true><<<dim3((Bb*TC)/128, Pp/64), dim3(256), 0, stream>>>(
        x, pT, featsC, Bb*TC, Pp, Dd, x2, p2, t0);
    k_gemm<2,false><<<dim3((Bb*TC)/128, G4/64), dim3(256), 0, stream>>>(
        featsC, WxT, xsC, Bb*TC, G4, Pp, nullptr, bx, 0);
    void* args[] = { (void*)&Whh, (void*)&xsC, (void*)&cbuf, (void*)&out, (void*)&flags, (void*)&t0 };
    hipLaunchCooperativeKernel((void*)k_lstm_persist, dim3(NG*WPG), dim3(512), args, 0, stream);
  }
}